// Round 19
// baseline (33.577 us; speedup 1.0000x reference)
//
#include <hip/hip_runtime.h>
#include <math.h>

#define G      26
#define NA     5
#define NC     20
#define NB     128
#define NT     1024
#define GG     (G*G)            // 676
#define CELLS  (NB*NA*GG)       // 432640
#define CH     (NC+5)           // 25
#define NWAVE  (CELLS/64)       // 6760 (exact)
#define NBLK   (NWAVE/4)        // 1690
#define IGNORE_THRESH 0.6f
#define OBJ_SCALE   5.0f
#define NOOBJ_SCALE 1.0f
#define CLS_SCALE   1.0f
#define COORD_SCALE 1.0f
#define STRIDE_F    32.0f

typedef float f32x4 __attribute__((ext_vector_type(4)));
typedef f32x4 uf32x4 __attribute__((aligned(4)));   // 4-B-aligned vector stores

__device__ __constant__ float c_aw[NA] = {1.08f, 3.42f, 6.63f, 9.42f, 16.62f};
__device__ __constant__ float c_ah[NA] = {1.19f, 4.41f, 11.38f, 5.11f, 10.52f};

// native: v_exp_f32 + v_rcp_f32 (~1 ulp; absmax threshold 604 >> this)
__device__ __forceinline__ float sigf(float v) {
    return __builtin_amdgcn_rcpf(1.0f + __expf(-v));
}

// -------- Pass 1 (single mega dispatch): streaming + embedded resolve/corr ----
// Streaming path: transform in registers, DIRECT plain stores (no LDS stage,
// no nontemporal). Each wave's 7 store instrs fully cover a contiguous 6.4 KB
// span -> L2 writeback merges partial lines (R8's amplification was the NT
// early-evict, not the stride). Blocks 0..255 also resolve 4 targets each +
// sparse corrections (unchanged from R18).
__launch_bounds__(256, 6)
__global__ void k_mega(const float* __restrict__ x,
                       const float* __restrict__ tg,
                       float* __restrict__ out,
                       float* __restrict__ partial) {
    __shared__ int   packed[NT];             // 4 KB (resolve blocks only)
    __shared__ float red[4];
    __shared__ float redc[4][9];

    int bid  = blockIdx.x;
    int tid  = threadIdx.x;
    int lane = tid & 63;
    int w    = tid >> 6;
    bool isres = bid < 256;                  // resolve-duty blocks

    if (isres) {
        #pragma unroll
        for (int q = 0; q < 4; ++q) {        // pack all NT targets (exact math)
            int t = tid + q * 256;
            int   b  = (int)tg[t * 6 + 0];
            float cx = tg[t * 6 + 2] * (float)G;
            float cy = tg[t * 6 + 3] * (float)G;
            float gw = tg[t * 6 + 4] * (float)G;
            float gh = tg[t * 6 + 5] * (float)G;
            int gi = (int)floorf(cx);
            int gj = (int)floorf(cy);
            float best = -1.0f;
            int bn = 0, bits = 0;
            #pragma unroll
            for (int a = 0; a < NA; ++a) {
                float inter = fminf(c_aw[a], gw) * fminf(c_ah[a], gh);
                float uni   = c_aw[a] * c_ah[a] + 1e-16f + gw * gh - inter;
                float iou   = inter / uni;
                if (iou > best) { best = iou; bn = a; }  // first max wins
                if (iou > IGNORE_THRESH) bits |= (1 << a);
            }
            int key = (b * G + gj) * G + gi;
            packed[t] = (key << 8) | (bn << 5) | bits;
        }
        __syncthreads();

        int t = bid * 4 + w;                 // wave -> target
        int me     = packed[t];
        int mykey  = me >> 8;
        int mybn   = (me >> 5) & 7;
        int mybits = me & 31;

        int agg = 0;                         // bits0-4 used, 5-9 earlier, 10 not-winner
        #pragma unroll
        for (int s = 0; s < 16; ++s) {
            int o  = lane + s * 64;
            int pv = packed[o];
            if ((pv >> 8) == mykey) {
                int obn = (pv >> 5) & 7;
                agg |= (1 << obn);
                if (o > t && obn == mybn) agg |= (1 << 10);
                if (o < t) agg |= (pv & 31) << 5;
            }
        }
        #pragma unroll
        for (int off = 32; off > 0; off >>= 1) agg |= __shfl_xor(agg, off);

        int used    = agg & 31;
        int earlier = (agg >> 5) & 31;
        bool winner = !(agg & (1 << 10));
        int cell0 = (mykey / GG) * (NA * GG) + (mykey % GG);

        float pc[9];                         // per-lane correction partial
        #pragma unroll
        for (int qq = 0; qq < 9; ++qq) pc[qq] = 0.0f;

        if (winner) {                        // wave-cooperative obj correction
            int cell = cell0 + mybn * GG;    // wave-uniform
            int pa = cell / GG;
            int sp = cell % GG;
            int an = pa % NA;
            float aw = c_aw[an], ah = c_ah[an];
            int i = sp % G, j = sp / G;

            // lane c loads channel c (25 parallel L2-hot loads)
            float vc = 0.0f;
            if (lane < CH)
                vc = x[(size_t)pa * (CH * GG) + (size_t)lane * GG + sp];
            float v0 = __shfl(vc, 0), v1 = __shfl(vc, 1);
            float v2 = __shfl(vc, 2), v3 = __shfl(vc, 3);
            float v4 = __shfl(vc, 4);

            // per-class BCE term on lanes 5..24, reduce across wave
            int label = (int)tg[t * 6 + 1];
            float clsterm = 0.0f;
            if (lane >= 5 && lane < CH) {
                int c = lane - 5;
                float pcv = fminf(fmaxf(sigf(vc), 1e-12f), 1.0f - 1e-12f);
                float tc = (c == label) ? 1.0f : 0.0f;
                clsterm = -(tc * __logf(pcv) + (1.0f - tc) * __logf(1.0f - pcv));
            }
            #pragma unroll
            for (int o = 32; o > 0; o >>= 1) clsterm += __shfl_down(clsterm, o);

            if (lane == 0) {                 // uniform scalars, lane 0 assembles
                float px = sigf(v0);
                float py = sigf(v1);
                float pconf = sigf(v4);
                float bx = px + (float)i;
                float by = py + (float)j;
                float bw = __expf(v2) * aw;
                float bh = __expf(v3) * ah;

                float cx = tg[t * 6 + 2] * (float)G;
                float cy = tg[t * 6 + 3] * (float)G;
                float gw2 = tg[t * 6 + 4] * (float)G;
                float gh2 = tg[t * 6 + 5] * (float)G;
                float tx = cx - floorf(cx);
                float ty = cy - floorf(cy);
                float tw = __logf(gw2 / aw + 1e-16f);
                float th = __logf(gh2 / ah + 1e-16f);

                float b1x1 = bx - bw * 0.5f, b1x2 = bx + bw * 0.5f;
                float b1y1 = by - bh * 0.5f, b1y2 = by + bh * 0.5f;
                float b2x1 = cx - gw2 * 0.5f, b2x2 = cx + gw2 * 0.5f;
                float b2y1 = cy - gh2 * 0.5f, b2y2 = cy + gh2 * 0.5f;
                float iw = fmaxf(fminf(b1x2, b2x2) - fmaxf(b1x1, b2x1) + 1.0f, 0.0f);
                float ih = fmaxf(fminf(b1y2, b2y2) - fmaxf(b1y1, b2y1) + 1.0f, 0.0f);
                float inter = iw * ih;
                float a1 = (b1x2 - b1x1 + 1.0f) * (b1y2 - b1y1 + 1.0f);
                float a2 = (b2x2 - b2x1 + 1.0f) * (b2y2 - b2y1 + 1.0f);
                float iou = inter / (a1 + a2 - inter + 1e-16f);

                pc[0] = (px - tx) * (px - tx);
                pc[1] = (py - ty) * (py - ty);
                pc[2] = (v2 - tw) * (v2 - tw);
                pc[3] = (v3 - th) * (v3 - th);
                pc[4] = (pconf - iou) * (pconf - iou);
                pc[6] = clsterm;
                pc[7] = 1.0f;                // n_obj
                pc[5] -= pconf * pconf;      // undo default noobj
                pc[8] -= 1.0f;
            }
        }
        if (lane < NA) {                     // supp corrections, one anchor/lane
            bool sflag = (mybits >> lane & 1) && !(earlier >> lane & 1)
                      && !(used >> lane & 1);
            if (sflag) {
                int cell = cell0 + lane * GG;
                int pa = cell / GG;
                int sp = cell % GG;
                float pconf = sigf(x[(size_t)(pa * CH + 4) * GG + sp]);
                pc[5] -= pconf * pconf;
                pc[8] -= 1.0f;
            }
        }
        #pragma unroll
        for (int o = 32; o > 0; o >>= 1) {
            #pragma unroll
            for (int qq = 0; qq < 9; ++qq) pc[qq] += __shfl_down(pc[qq], o);
        }
        if (lane == 0) {
            #pragma unroll
            for (int qq = 0; qq < 9; ++qq) redc[w][qq] = pc[qq];
        }
    }

    // ---------------- streaming (all blocks; direct plain stores) ----------------
    // bijective XCD-chunk swizzle: NBLK = 1690 = 8*211 + 2
    const int q = NBLK / 8, r = NBLK % 8;
    int xcd = bid & 7;
    int pos = bid >> 3;
    int blk = (xcd < r) ? xcd * (q + 1) + pos
                        : r * (q + 1) + (xcd - r) * q + pos;

    int gw   = blk * 4 + w;                  // global wave id
    int cell = gw * 64 + lane;

    int pa = cell / GG;                      // b*NA + a
    int sp = cell % GG;
    int an = pa % NA;
    float aw = c_aw[an], ah = c_ah[an];
    int i = sp % G, j = sp / G;

    const float* xp = x + (size_t)pa * (CH * GG) + sp;
    float v[CH];
    #pragma unroll
    for (int c = 0; c < CH; ++c) v[c] = xp[(size_t)c * GG];

    float pconf = sigf(v[4]);
    float o0 = (sigf(v[0]) + (float)i) * STRIDE_F;
    float o1 = (sigf(v[1]) + (float)j) * STRIDE_F;
    float o2 = __expf(v[2]) * aw * STRIDE_F;
    float o3 = __expf(v[3]) * ah * STRIDE_F;
    float oc[NC];
    #pragma unroll
    for (int c = 0; c < NC; ++c) oc[c] = sigf(v[5 + c]);

    // direct per-cell store: 100 B contiguous; wave's 7 instrs cover 6.4 KB.
    float* op = out + (size_t)cell * CH;
    uf32x4* op4 = (uf32x4*)op;
    op4[0] = (f32x4){o0, o1, o2, o3};
    op4[1] = (f32x4){pconf, oc[0], oc[1], oc[2]};
    op4[2] = (f32x4){oc[3], oc[4], oc[5], oc[6]};
    op4[3] = (f32x4){oc[7], oc[8], oc[9], oc[10]};
    op4[4] = (f32x4){oc[11], oc[12], oc[13], oc[14]};
    op4[5] = (f32x4){oc[15], oc[16], oc[17], oc[18]};
    op[24] = oc[19];

    // default noobj sum
    float p5 = pconf * pconf;
    #pragma unroll
    for (int o = 32; o > 0; o >>= 1) p5 += __shfl_down(p5, o);
    if (lane == 0) red[w] = p5;
    __syncthreads();                         // end-of-kernel: drain ~free
    if (tid == 0)
        partial[(size_t)bid * 16] = red[0] + red[1] + red[2] + red[3];
    if (tid < 9)
        partial[(size_t)bid * 16 + 1 + tid] =
            isres ? (redc[0][tid] + redc[1][tid] + redc[2][tid] + redc[3][tid])
                  : 0.0f;
}

// -------- Pass 2: reduce per-block records + finalize --------
__launch_bounds__(1024)
__global__ void k_final(const float* __restrict__ partial,
                        float* __restrict__ loss_out) {
    __shared__ float red[16][10];
    int t = threadIdx.x;

    float p[10] = {0, 0, 0, 0, 0, 0, 0, 0, 0, 0};
    for (int sIdx = t; sIdx < NBLK; sIdx += 1024) {
        const f32x4* q4 = (const f32x4*)(partial + (size_t)sIdx * 16);
        f32x4 A = q4[0], B = q4[1];
        p[0] += A.x; p[1] += A.y; p[2] += A.z; p[3] += A.w;
        p[4] += B.x; p[5] += B.y; p[6] += B.z; p[7] += B.w;
        p[8] += partial[(size_t)sIdx * 16 + 8];
        p[9] += partial[(size_t)sIdx * 16 + 9];
    }

    #pragma unroll
    for (int o = 32; o > 0; o >>= 1) {
        #pragma unroll
        for (int q = 0; q < 10; ++q) p[q] += __shfl_down(p[q], o);
    }
    int lane = t & 63, wid = t >> 6;
    if (lane == 0) {
        #pragma unroll
        for (int q = 0; q < 10; ++q) red[wid][q] = p[q];
    }
    __syncthreads();

    if (t == 0) {
        float sv[10];
        #pragma unroll
        for (int q = 0; q < 10; ++q) {
            float acc_q = 0.0f;
            for (int ww = 0; ww < 16; ++ww) acc_q += red[ww][q];
            sv[q] = acc_q;
        }
        // sv[0]=default noobj sum; sv[1+q]=corr p_q (q=0..8)
        float n_obj   = sv[8];
        float n_noobj = (float)CELLS + sv[9];
        float l = COORD_SCALE * (sv[1] + sv[2] + sv[3] + sv[4]) / n_obj
                + OBJ_SCALE * sv[5] / n_obj
                + NOOBJ_SCALE * (sv[0] + sv[6]) / n_noobj
                + CLS_SCALE * sv[7] / (n_obj * (float)NC);
        *loss_out = l;
    }
}

extern "C" void kernel_launch(void* const* d_in, const int* in_sizes, int n_in,
                              void* d_out, int out_size, void* d_ws, size_t ws_size,
                              hipStream_t stream) {
    const float* x  = (const float*)d_in[0];
    const float* tg = (const float*)d_in[1];
    float* out = (float*)d_out;

    float* partial = (float*)d_ws;           // NBLK*16 floats (108 KB)

    k_mega<<<NBLK, 256, 0, stream>>>(x, tg, out, partial);
    k_final<<<1, 1024, 0, stream>>>(partial, out + (size_t)CELLS * CH);
}

// Round 20
// 24.341 us; speedup vs baseline: 1.3795x; 1.3795x over previous
//
#include <hip/hip_runtime.h>
#include <math.h>

#define G      26
#define NA     5
#define NC     20
#define NB     128
#define NT     1024
#define GG     (G*G)            // 676
#define CELLS  (NB*NA*GG)       // 432640
#define CH     (NC+5)           // 25
#define NWAVE  (CELLS/64)       // 6760 (exact)
#define NBLK   (NWAVE/4)        // 1690
#define IGNORE_THRESH 0.6f
#define OBJ_SCALE   5.0f
#define NOOBJ_SCALE 1.0f
#define CLS_SCALE   1.0f
#define COORD_SCALE 1.0f
#define STRIDE_F    32.0f

typedef float f32x4 __attribute__((ext_vector_type(4)));

__device__ __constant__ float c_aw[NA] = {1.08f, 3.42f, 6.63f, 9.42f, 16.62f};
__device__ __constant__ float c_ah[NA] = {1.19f, 4.41f, 11.38f, 5.11f, 10.52f};

// native: v_exp_f32 + v_rcp_f32 (~1 ulp; absmax threshold 604 >> this)
__device__ __forceinline__ float sigf(float v) {
    return __builtin_amdgcn_rcpf(1.0f + __expf(-v));
}

// -------- Pass 1 (single mega dispatch): streaming + embedded resolve/corr ----
// R18 verbatim (best measured, 24.2us). Streaming via wave-local LDS transpose
// + coalesced NT stores (direct per-thread stores proven -9us worse, R19).
__launch_bounds__(256, 6)
__global__ void k_mega(const float* __restrict__ x,
                       const float* __restrict__ tg,
                       float* __restrict__ out,
                       float* __restrict__ partial) {
    __shared__ float stageAll[4][64 * CH];   // 25600 B; first 4 KB doubles as packed[]
    __shared__ float red[4];
    __shared__ float redc[4][9];

    int bid  = blockIdx.x;
    int tid  = threadIdx.x;
    int lane = tid & 63;
    int w    = tid >> 6;
    bool isres = bid < 256;                  // resolve-duty blocks

    if (isres) {
        int* packed = (int*)&stageAll[0][0]; // overlay: resolve phase only

        #pragma unroll
        for (int q = 0; q < 4; ++q) {        // pack all NT targets (exact math)
            int t = tid + q * 256;
            int   b  = (int)tg[t * 6 + 0];
            float cx = tg[t * 6 + 2] * (float)G;
            float cy = tg[t * 6 + 3] * (float)G;
            float gw = tg[t * 6 + 4] * (float)G;
            float gh = tg[t * 6 + 5] * (float)G;
            int gi = (int)floorf(cx);
            int gj = (int)floorf(cy);
            float best = -1.0f;
            int bn = 0, bits = 0;
            #pragma unroll
            for (int a = 0; a < NA; ++a) {
                float inter = fminf(c_aw[a], gw) * fminf(c_ah[a], gh);
                float uni   = c_aw[a] * c_ah[a] + 1e-16f + gw * gh - inter;
                float iou   = inter / uni;
                if (iou > best) { best = iou; bn = a; }  // first max wins
                if (iou > IGNORE_THRESH) bits |= (1 << a);
            }
            int key = (b * G + gj) * G + gi;
            packed[t] = (key << 8) | (bn << 5) | bits;
        }
        __syncthreads();

        int t = bid * 4 + w;                 // wave -> target
        int me     = packed[t];
        int mykey  = me >> 8;
        int mybn   = (me >> 5) & 7;
        int mybits = me & 31;

        int agg = 0;                         // bits0-4 used, 5-9 earlier, 10 not-winner
        #pragma unroll
        for (int s = 0; s < 16; ++s) {
            int o  = lane + s * 64;
            int pv = packed[o];
            if ((pv >> 8) == mykey) {
                int obn = (pv >> 5) & 7;
                agg |= (1 << obn);
                if (o > t && obn == mybn) agg |= (1 << 10);
                if (o < t) agg |= (pv & 31) << 5;
            }
        }
        #pragma unroll
        for (int off = 32; off > 0; off >>= 1) agg |= __shfl_xor(agg, off);
        __syncthreads();                     // packed reads done: stage reuse safe

        int used    = agg & 31;
        int earlier = (agg >> 5) & 31;
        bool winner = !(agg & (1 << 10));
        int cell0 = (mykey / GG) * (NA * GG) + (mykey % GG);

        float pc[9];                         // per-lane correction partial
        #pragma unroll
        for (int qq = 0; qq < 9; ++qq) pc[qq] = 0.0f;

        if (winner) {                        // wave-cooperative obj correction
            int cell = cell0 + mybn * GG;    // wave-uniform
            int pa = cell / GG;
            int sp = cell % GG;
            int an = pa % NA;
            float aw = c_aw[an], ah = c_ah[an];
            int i = sp % G, j = sp / G;

            // lane c loads channel c (25 parallel L2-hot loads)
            float vc = 0.0f;
            if (lane < CH)
                vc = x[(size_t)pa * (CH * GG) + (size_t)lane * GG + sp];
            float v0 = __shfl(vc, 0), v1 = __shfl(vc, 1);
            float v2 = __shfl(vc, 2), v3 = __shfl(vc, 3);
            float v4 = __shfl(vc, 4);

            // per-class BCE term on lanes 5..24, reduce across wave
            int label = (int)tg[t * 6 + 1];
            float clsterm = 0.0f;
            if (lane >= 5 && lane < CH) {
                int c = lane - 5;
                float pcv = fminf(fmaxf(sigf(vc), 1e-12f), 1.0f - 1e-12f);
                float tc = (c == label) ? 1.0f : 0.0f;
                clsterm = -(tc * __logf(pcv) + (1.0f - tc) * __logf(1.0f - pcv));
            }
            #pragma unroll
            for (int o = 32; o > 0; o >>= 1) clsterm += __shfl_down(clsterm, o);

            if (lane == 0) {                 // uniform scalars, lane 0 assembles
                float px = sigf(v0);
                float py = sigf(v1);
                float pconf = sigf(v4);
                float bx = px + (float)i;
                float by = py + (float)j;
                float bw = __expf(v2) * aw;
                float bh = __expf(v3) * ah;

                float cx = tg[t * 6 + 2] * (float)G;
                float cy = tg[t * 6 + 3] * (float)G;
                float gw2 = tg[t * 6 + 4] * (float)G;
                float gh2 = tg[t * 6 + 5] * (float)G;
                float tx = cx - floorf(cx);
                float ty = cy - floorf(cy);
                float tw = __logf(gw2 / aw + 1e-16f);
                float th = __logf(gh2 / ah + 1e-16f);

                float b1x1 = bx - bw * 0.5f, b1x2 = bx + bw * 0.5f;
                float b1y1 = by - bh * 0.5f, b1y2 = by + bh * 0.5f;
                float b2x1 = cx - gw2 * 0.5f, b2x2 = cx + gw2 * 0.5f;
                float b2y1 = cy - gh2 * 0.5f, b2y2 = cy + gh2 * 0.5f;
                float iw = fmaxf(fminf(b1x2, b2x2) - fmaxf(b1x1, b2x1) + 1.0f, 0.0f);
                float ih = fmaxf(fminf(b1y2, b2y2) - fmaxf(b1y1, b2y1) + 1.0f, 0.0f);
                float inter = iw * ih;
                float a1 = (b1x2 - b1x1 + 1.0f) * (b1y2 - b1y1 + 1.0f);
                float a2 = (b2x2 - b2x1 + 1.0f) * (b2y2 - b2y1 + 1.0f);
                float iou = inter / (a1 + a2 - inter + 1e-16f);

                pc[0] = (px - tx) * (px - tx);
                pc[1] = (py - ty) * (py - ty);
                pc[2] = (v2 - tw) * (v2 - tw);
                pc[3] = (v3 - th) * (v3 - th);
                pc[4] = (pconf - iou) * (pconf - iou);
                pc[6] = clsterm;
                pc[7] = 1.0f;                // n_obj
                pc[5] -= pconf * pconf;      // undo default noobj
                pc[8] -= 1.0f;
            }
        }
        if (lane < NA) {                     // supp corrections, one anchor/lane
            bool sflag = (mybits >> lane & 1) && !(earlier >> lane & 1)
                      && !(used >> lane & 1);
            if (sflag) {
                int cell = cell0 + lane * GG;
                int pa = cell / GG;
                int sp = cell % GG;
                float pconf = sigf(x[(size_t)(pa * CH + 4) * GG + sp]);
                pc[5] -= pconf * pconf;
                pc[8] -= 1.0f;
            }
        }
        #pragma unroll
        for (int o = 32; o > 0; o >>= 1) {
            #pragma unroll
            for (int qq = 0; qq < 9; ++qq) pc[qq] += __shfl_down(pc[qq], o);
        }
        if (lane == 0) {
            #pragma unroll
            for (int qq = 0; qq < 9; ++qq) redc[w][qq] = pc[qq];
        }
    }

    // ---------------- streaming (all blocks; R17 body) ----------------
    // bijective XCD-chunk swizzle: NBLK = 1690 = 8*211 + 2
    const int q = NBLK / 8, r = NBLK % 8;
    int xcd = bid & 7;
    int pos = bid >> 3;
    int blk = (xcd < r) ? xcd * (q + 1) + pos
                        : r * (q + 1) + (xcd - r) * q + pos;

    int gw   = blk * 4 + w;                  // global wave id
    int cell = gw * 64 + lane;

    int pa = cell / GG;                      // b*NA + a
    int sp = cell % GG;
    int an = pa % NA;
    float aw = c_aw[an], ah = c_ah[an];
    int i = sp % G, j = sp / G;

    const float* xp = x + (size_t)pa * (CH * GG) + sp;
    float v[CH];
    #pragma unroll
    for (int c = 0; c < CH; ++c) v[c] = xp[(size_t)c * GG];

    float pconf = sigf(v[4]);

    float* s = &stageAll[w][lane * CH];      // stride 25 (odd): 2-way, free
    s[0] = (sigf(v[0]) + (float)i) * STRIDE_F;
    s[1] = (sigf(v[1]) + (float)j) * STRIDE_F;
    s[2] = __expf(v[2]) * aw * STRIDE_F;
    s[3] = __expf(v[3]) * ah * STRIDE_F;
    s[4] = pconf;
    #pragma unroll
    for (int c = 0; c < NC; ++c) s[5 + c] = sigf(v[5 + c]);

    // wave-local transpose read + nontemporal store (400 f4 per wave)
    const f32x4* st = (const f32x4*)stageAll[w];
    f32x4* ob = (f32x4*)(out + (size_t)gw * (64 * CH));
    #pragma unroll
    for (int rr = 0; rr < 6; ++rr)
        __builtin_nontemporal_store(st[rr * 64 + lane], &ob[rr * 64 + lane]);
    if (lane < 16)
        __builtin_nontemporal_store(st[384 + lane], &ob[384 + lane]);

    // default noobj sum
    float p5 = pconf * pconf;
    #pragma unroll
    for (int o = 32; o > 0; o >>= 1) p5 += __shfl_down(p5, o);
    if (lane == 0) red[w] = p5;
    __syncthreads();                         // end-of-kernel: drain ~free
    if (tid == 0)
        partial[(size_t)bid * 16] = red[0] + red[1] + red[2] + red[3];
    if (tid < 9)
        partial[(size_t)bid * 16 + 1 + tid] =
            isres ? (redc[0][tid] + redc[1][tid] + redc[2][tid] + redc[3][tid])
                  : 0.0f;
}

// -------- Pass 2: reduce per-block records + finalize --------
__launch_bounds__(1024)
__global__ void k_final(const float* __restrict__ partial,
                        float* __restrict__ loss_out) {
    __shared__ float red[16][10];
    int t = threadIdx.x;

    float p[10] = {0, 0, 0, 0, 0, 0, 0, 0, 0, 0};
    for (int sIdx = t; sIdx < NBLK; sIdx += 1024) {
        const f32x4* q4 = (const f32x4*)(partial + (size_t)sIdx * 16);
        f32x4 A = q4[0], B = q4[1];
        p[0] += A.x; p[1] += A.y; p[2] += A.z; p[3] += A.w;
        p[4] += B.x; p[5] += B.y; p[6] += B.z; p[7] += B.w;
        p[8] += partial[(size_t)sIdx * 16 + 8];
        p[9] += partial[(size_t)sIdx * 16 + 9];
    }

    #pragma unroll
    for (int o = 32; o > 0; o >>= 1) {
        #pragma unroll
        for (int q = 0; q < 10; ++q) p[q] += __shfl_down(p[q], o);
    }
    int lane = t & 63, wid = t >> 6;
    if (lane == 0) {
        #pragma unroll
        for (int q = 0; q < 10; ++q) red[wid][q] = p[q];
    }
    __syncthreads();

    if (t == 0) {
        float sv[10];
        #pragma unroll
        for (int q = 0; q < 10; ++q) {
            float acc_q = 0.0f;
            for (int ww = 0; ww < 16; ++ww) acc_q += red[ww][q];
            sv[q] = acc_q;
        }
        // sv[0]=default noobj sum; sv[1+q]=corr p_q (q=0..8)
        float n_obj   = sv[8];
        float n_noobj = (float)CELLS + sv[9];
        float l = COORD_SCALE * (sv[1] + sv[2] + sv[3] + sv[4]) / n_obj
                + OBJ_SCALE * sv[5] / n_obj
                + NOOBJ_SCALE * (sv[0] + sv[6]) / n_noobj
                + CLS_SCALE * sv[7] / (n_obj * (float)NC);
        *loss_out = l;
    }
}

extern "C" void kernel_launch(void* const* d_in, const int* in_sizes, int n_in,
                              void* d_out, int out_size, void* d_ws, size_t ws_size,
                              hipStream_t stream) {
    const float* x  = (const float*)d_in[0];
    const float* tg = (const float*)d_in[1];
    float* out = (float*)d_out;

    float* partial = (float*)d_ws;           // NBLK*16 floats (108 KB)

    k_mega<<<NBLK, 256, 0, stream>>>(x, tg, out, partial);
    k_final<<<1, 1024, 0, stream>>>(partial, out + (size_t)CELLS * CH);
}